// Round 2
// baseline (109.196 us; speedup 1.0000x reference)
//
#include <hip/hip_runtime.h>
#include <stdint.h>

// Problem: x [2048][1024] f32, W [1024][4096] f32,
// out [2048][4096] f32 = x@W - 0.5*(||x_b||^2 + ||w_o||^2)
#define BATCH 2048
#define DIN   1024
#define DOUT  4096

// ---------- helpers ----------

// fp32 -> bf16 bits, round-to-nearest-even (finite normals; no NaN path)
__device__ __forceinline__ ushort f2bf(float f) {
    uint32_t u = __float_as_uint(f);
    u += 0x7fffu + ((u >> 16) & 1u);
    return (ushort)(u >> 16);
}

// async global->LDS direct copy, 16B per lane. LDS dest is wave-uniform base;
// HW writes lane i's 16B at ldsbase + i*16 (m97/m104).
__device__ __forceinline__ void async_copy16(const void* gsrc, void* ldst) {
    __builtin_amdgcn_global_load_lds(
        reinterpret_cast<uint32_t __attribute__((address_space(1)))*>(
            reinterpret_cast<uintptr_t>(gsrc)),
        reinterpret_cast<uint32_t __attribute__((address_space(3)))*>(
            reinterpret_cast<uintptr_t>(ldst)),
        16, 0, 0);
}

typedef __bf16 bf16x8 __attribute__((ext_vector_type(8)));
typedef float  f32x4  __attribute__((ext_vector_type(4)));

// ---------- fused prep ----------
// blocks [0,2048): row of x -> bf16 cast + row sum-of-squares (xsq)
// blocks [2048,3072): 64x64 transpose tile of W -> bf16 W^T + column
//   sum-of-squares PARTIALS (wsq_part[16][DOUT], no atomics, no pre-zero)
__global__ __launch_bounds__(256) void prep_fused(
    const float* __restrict__ x, const float* __restrict__ W,
    ushort* __restrict__ xb, ushort* __restrict__ wbt,
    float* __restrict__ xsq, float* __restrict__ wsq_part)
{
    __shared__ float smem[64 * 65 + 64];  // prep_w tile + csum; prep_x uses [0..3]
    const int t = threadIdx.x;

    if (blockIdx.x < BATCH) {
        // ---- prep_x ----
        const int row = blockIdx.x;
        const float4 v = *(const float4*)(x + (size_t)row * DIN + t * 4);
        ushort4 pk;
        pk.x = f2bf(v.x); pk.y = f2bf(v.y); pk.z = f2bf(v.z); pk.w = f2bf(v.w);
        *(ushort4*)(xb + (size_t)row * DIN + t * 4) = pk;

        float s = v.x * v.x + v.y * v.y + v.z * v.z + v.w * v.w;
        #pragma unroll
        for (int off = 32; off > 0; off >>= 1) s += __shfl_down(s, off);
        if ((t & 63) == 0) smem[t >> 6] = s;
        __syncthreads();
        if (t == 0) xsq[row] = smem[0] + smem[1] + smem[2] + smem[3];
    } else {
        // ---- prep_w ----
        const int wblk = blockIdx.x - BATCH;          // 0..1023
        const int o0 = (wblk & 63) * 64;              // 64 chunks over DOUT
        const int i0 = (wblk >> 6) * 64;              // 16 chunks over DIN
        float (*tile)[65] = (float(*)[65])smem;       // +1 pad
        float* csum = smem + 64 * 65;
        const int c4 = (t & 15) * 4;
        const int r0 = t >> 4;

        if (t < 64) csum[t] = 0.f;
        __syncthreads();

        float ss0 = 0.f, ss1 = 0.f, ss2 = 0.f, ss3 = 0.f;
        #pragma unroll
        for (int p = 0; p < 4; ++p) {                 // coalesced float4 rows
            const int r = r0 + p * 16;
            const float4 v = *(const float4*)&W[(size_t)(i0 + r) * DOUT + o0 + c4];
            tile[r][c4 + 0] = v.x; tile[r][c4 + 1] = v.y;
            tile[r][c4 + 2] = v.z; tile[r][c4 + 3] = v.w;
            ss0 += v.x * v.x; ss1 += v.y * v.y;
            ss2 += v.z * v.z; ss3 += v.w * v.w;
        }
        atomicAdd(&csum[c4 + 0], ss0);
        atomicAdd(&csum[c4 + 1], ss1);
        atomicAdd(&csum[c4 + 2], ss2);
        atomicAdd(&csum[c4 + 3], ss3);
        __syncthreads();
        if (t < 64) wsq_part[(size_t)(wblk >> 6) * DOUT + o0 + t] = csum[t];

        #pragma unroll
        for (int p = 0; p < 4; ++p) {                 // coalesced ushort4 W^T rows
            const int orow = r0 + p * 16;
            ushort4 pk;
            pk.x = f2bf(tile[c4 + 0][orow]);
            pk.y = f2bf(tile[c4 + 1][orow]);
            pk.z = f2bf(tile[c4 + 2][orow]);
            pk.w = f2bf(tile[c4 + 3][orow]);
            *(ushort4*)&wbt[(size_t)(o0 + orow) * DIN + i0 + c4] = pk;
        }
    }
}

// ---------- GEMM + epilogue ----------
// A = xb [BATCH][DIN] bf16, Bt = wbt [DOUT][DIN] bf16, out fp32.
// 128x128 tile, BK=32, ring of 4 LDS buffers, prefetch distance 3,
// counted vmcnt (T4) + one raw s_barrier per K-step + setprio (T5).
// LDS rows are 64B = 4 chunks of 16B; swizzle slot ^= (row>>1)&3 ->
// 2-way banks (free, m136). Applied both-sides (rule 21): linear
// global_load_lds dest + pre-swizzled global SOURCE + swizzled ds_read.
#define BM 128
#define BN 128
#define BK 32
#define NSTEP (DIN / BK)   // 32 K-steps

__global__ __launch_bounds__(256, 2) void gemm_epi(
    const ushort* __restrict__ A,
    const ushort* __restrict__ Bt,
    const float* __restrict__ xsq,
    const float* __restrict__ wsq_part,
    float* __restrict__ out)
{
    __shared__ __align__(16) ushort sA[4][BM * BK];  // 4 x 8 KiB
    __shared__ __align__(16) ushort sB[4][BN * BK];  // 4 x 8 KiB

    const int tid  = threadIdx.x;
    const int wv   = tid >> 6;
    const int lane = tid & 63;
    const int wr = wv >> 1, wc = wv & 1;

    // XCD swizzle: grid 512 (32x16), 8 super-tiles of 8x8 blocks; XCD k's 64
    // blocks touch 8 A-panels + 8 B-panels = 4 MiB = its L2. 512%8==0 (bijective).
    const int bid = blockIdx.x;
    const int xcd = bid & 7, loc = bid >> 3;
    const int bx = (xcd & 3) * 8 + (loc & 7);        // 0..31 over DOUT
    const int by = (xcd >> 2) * 8 + (loc >> 3);      // 0..15 over BATCH
    const int m0 = by * BM;
    const int n0 = bx * BN;

    // ---- staging geometry ----
    // Dest chunk (linear HW order) for wave wv, instr q: c = wv*128 + q*64 + lane
    //   -> row = c>>2 = wv*32 + q*16 + (lane>>2), phys slot = lane&3.
    // Content requirement: LDS(row, ps) = global chunk ps ^ ((row>>1)&3).
    const int srow = wv * 32 + (lane >> 2);
    const int scol = (((lane & 3) ^ ((lane >> 3) & 3)) << 3);  // ushorts
    const ushort* ag = A  + (size_t)(m0 + srow) * DIN + scol;
    const ushort* bg = Bt + (size_t)(n0 + srow) * DIN + scol;

    // ---- fragment geometry ----
    // A-op lane holds A[m=lane&15][k=(lane>>4)*8+j]; logical chunk = lane>>4,
    // physical = logical ^ ((row>>1)&3), row bits 1-2 come from lane&15 only.
    const int fr   = lane & 15;
    const int kq   = lane >> 4;
    const int sw   = (fr >> 1) & 3;
    const int off8 = ((kq ^ sw) << 3);               // ushort offset within row
    const int arow = wr * 64 + fr;
    const int brow = wc * 64 + fr;

    f32x4 acc[4][4] = {};

    auto stage = [&](int set) {                       // 4 loads/wave/set
        const int sl = set & 3;
        const int kt = set * BK;
        ushort* da = &sA[sl][wv * 1024];              // wave-uniform base
        ushort* db = &sB[sl][wv * 1024];
        async_copy16(ag + kt,                 da);
        async_copy16(ag + kt + 16 * DIN,      da + 512);
        async_copy16(bg + kt,                 db);
        async_copy16(bg + kt + 16 * DIN,      db + 512);
    };

    // prologue: prefetch sets 0,1,2 (12 loads in flight/wave)
    stage(0); stage(1); stage(2);

    // Per step s: vmcnt(vm) guarantees MY set-s loads landed; barrier makes that
    // all-waves; issue set s+3 AFTER the barrier (its slot was read at s-1, and
    // crossing this barrier proves every wave finished those ds_reads).
    // vm: steps <=29 have sets {s+1,s+2} to keep in flight -> 8; step 30 -> 4;
    // step 31 -> 0.
#define K_STEP(s, vm) do {                                                    \
    asm volatile("s_waitcnt vmcnt(" #vm ")" ::: "memory");                    \
    __builtin_amdgcn_s_barrier();                                             \
    asm volatile("" ::: "memory");                                            \
    if ((s) + 3 < NSTEP) stage((s) + 3);                                      \
    const ushort* pa_ = &sA[(s) & 3][0];                                      \
    const ushort* pb_ = &sB[(s) & 3][0];                                      \
    bf16x8 fa[4], fb[4];                                                      \
    _Pragma("unroll") for (int i = 0; i < 4; ++i) {                           \
        fa[i] = *(const bf16x8*)&pa_[(arow + i * 16) * BK + off8];            \
        fb[i] = *(const bf16x8*)&pb_[(brow + i * 16) * BK + off8];            \
    }                                                                         \
    __builtin_amdgcn_s_setprio(1);                                            \
    _Pragma("unroll") for (int mi = 0; mi < 4; ++mi)                          \
    _Pragma("unroll") for (int ni = 0; ni < 4; ++ni)                          \
        acc[mi][ni] = __builtin_amdgcn_mfma_f32_16x16x32_bf16(                \
            fa[mi], fb[ni], acc[mi][ni], 0, 0, 0);                            \
    __builtin_amdgcn_s_setprio(0);                                            \
} while (0)

    #pragma unroll
    for (int s = 0; s < NSTEP - 4; ++s) K_STEP(s, 8);
    K_STEP(28, 8);
    K_STEP(29, 8);
    K_STEP(30, 4);
    K_STEP(31, 0);
#undef K_STEP

    // Epilogue. C/D layout (m89/m91): col = lane&15, row = (lane>>4)*4 + r.
    const int er = (lane >> 4) * 4;
    const int ec = lane & 15;

    // wterm: sum the 16 i-block partials per output column (L2-hit loads)
    float wt[4];
    #pragma unroll
    for (int ni = 0; ni < 4; ++ni) {
        const int col = n0 + wc * 64 + ni * 16 + ec;
        float s = 0.f;
        #pragma unroll
        for (int j = 0; j < 16; ++j) s += wsq_part[(size_t)j * DOUT + col];
        wt[ni] = s;
    }

    #pragma unroll
    for (int mi = 0; mi < 4; ++mi) {
        const int row = m0 + wr * 64 + mi * 16 + er;
        #pragma unroll
        for (int ni = 0; ni < 4; ++ni) {
            const int col = n0 + wc * 64 + ni * 16 + ec;
            #pragma unroll
            for (int r = 0; r < 4; ++r) {
                out[(size_t)(row + r) * DOUT + col] =
                    acc[mi][ni][r] - 0.5f * (xsq[row + r] + wt[ni]);
            }
        }
    }
}

// ---------- launch ----------

extern "C" void kernel_launch(void* const* d_in, const int* in_sizes, int n_in,
                              void* d_out, int out_size, void* d_ws, size_t ws_size,
                              hipStream_t stream) {
    const float* x = (const float*)d_in[0];
    const float* W = (const float*)d_in[1];
    float* out = (float*)d_out;

    // Workspace layout (~12.3 MiB):
    //   [0, 4MiB)              xb       : bf16 x   [2048][1024]
    //   [4MiB, 12MiB)          wbt      : bf16 W^T [4096][1024]
    //   [12MiB, +8KiB)         xsq      : f32 [2048]
    //   [12MiB+16KiB, +256KiB) wsq_part : f32 [16][4096]
    char* ws = (char*)d_ws;
    ushort* xb  = (ushort*)ws;
    ushort* wbt = (ushort*)(ws + (4u << 20));
    float*  xsq = (float*)(ws + (12u << 20));
    float*  wsq_part = (float*)(ws + (12u << 20) + (16u << 10));

    prep_fused<<<BATCH + (DOUT / 64) * (DIN / 64), 256, 0, stream>>>(
        x, W, xb, wbt, xsq, wsq_part);
    gemm_epi<<<(DOUT / BN) * (BATCH / BM), 256, 0, stream>>>(
        xb, wbt, xsq, wsq_part, out);
}

// Round 3
// 106.276 us; speedup vs baseline: 1.0275x; 1.0275x over previous
//
#include <hip/hip_runtime.h>
#include <stdint.h>

// Problem: x [2048][1024] f32, W [1024][4096] f32,
// out [2048][4096] f32 = x@W - 0.5*(||x_b||^2 + ||w_o||^2)
#define BATCH 2048
#define DIN   1024
#define DOUT  4096

// ---------- helpers ----------

// fp32 -> bf16 bits, round-to-nearest-even (finite normals; no NaN path)
__device__ __forceinline__ ushort f2bf(float f) {
    uint32_t u = __float_as_uint(f);
    u += 0x7fffu + ((u >> 16) & 1u);
    return (ushort)(u >> 16);
}

// async global->LDS direct copy, 16B per lane. LDS dest is wave-uniform base;
// HW writes lane i's 16B at ldsbase + i*16 (m97/m104).
__device__ __forceinline__ void async_copy16(const void* gsrc, void* ldst) {
    __builtin_amdgcn_global_load_lds(
        reinterpret_cast<uint32_t __attribute__((address_space(1)))*>(
            reinterpret_cast<uintptr_t>(gsrc)),
        reinterpret_cast<uint32_t __attribute__((address_space(3)))*>(
            reinterpret_cast<uintptr_t>(ldst)),
        16, 0, 0);
}

typedef __bf16 bf16x8 __attribute__((ext_vector_type(8)));
typedef float  f32x4  __attribute__((ext_vector_type(4)));

// ---------- fused prep ----------
// blocks [0,2048): row of x -> bf16 cast + row sum-of-squares (xsq)
// blocks [2048,3072): 64x64 transpose tile of W -> bf16 W^T + column
//   sum-of-squares PARTIALS (wsq_part[16][DOUT], no atomics, no pre-zero)
__global__ __launch_bounds__(256) void prep_fused(
    const float* __restrict__ x, const float* __restrict__ W,
    ushort* __restrict__ xb, ushort* __restrict__ wbt,
    float* __restrict__ xsq, float* __restrict__ wsq_part)
{
    __shared__ float smem[64 * 65 + 64];  // prep_w tile + csum; prep_x uses [0..3]
    const int t = threadIdx.x;

    if (blockIdx.x < BATCH) {
        // ---- prep_x ----
        const int row = blockIdx.x;
        const float4 v = *(const float4*)(x + (size_t)row * DIN + t * 4);
        ushort4 pk;
        pk.x = f2bf(v.x); pk.y = f2bf(v.y); pk.z = f2bf(v.z); pk.w = f2bf(v.w);
        *(ushort4*)(xb + (size_t)row * DIN + t * 4) = pk;

        float s = v.x * v.x + v.y * v.y + v.z * v.z + v.w * v.w;
        #pragma unroll
        for (int off = 32; off > 0; off >>= 1) s += __shfl_down(s, off);
        if ((t & 63) == 0) smem[t >> 6] = s;
        __syncthreads();
        if (t == 0) xsq[row] = smem[0] + smem[1] + smem[2] + smem[3];
    } else {
        // ---- prep_w ----
        const int wblk = blockIdx.x - BATCH;          // 0..1023
        const int o0 = (wblk & 63) * 64;              // 64 chunks over DOUT
        const int i0 = (wblk >> 6) * 64;              // 16 chunks over DIN
        float (*tile)[65] = (float(*)[65])smem;       // +1 pad
        float* csum = smem + 64 * 65;
        const int c4 = (t & 15) * 4;
        const int r0 = t >> 4;

        if (t < 64) csum[t] = 0.f;
        __syncthreads();

        float ss0 = 0.f, ss1 = 0.f, ss2 = 0.f, ss3 = 0.f;
        #pragma unroll
        for (int p = 0; p < 4; ++p) {                 // coalesced float4 rows
            const int r = r0 + p * 16;
            const float4 v = *(const float4*)&W[(size_t)(i0 + r) * DOUT + o0 + c4];
            tile[r][c4 + 0] = v.x; tile[r][c4 + 1] = v.y;
            tile[r][c4 + 2] = v.z; tile[r][c4 + 3] = v.w;
            ss0 += v.x * v.x; ss1 += v.y * v.y;
            ss2 += v.z * v.z; ss3 += v.w * v.w;
        }
        atomicAdd(&csum[c4 + 0], ss0);
        atomicAdd(&csum[c4 + 1], ss1);
        atomicAdd(&csum[c4 + 2], ss2);
        atomicAdd(&csum[c4 + 3], ss3);
        __syncthreads();
        if (t < 64) wsq_part[(size_t)(wblk >> 6) * DOUT + o0 + t] = csum[t];

        #pragma unroll
        for (int p = 0; p < 4; ++p) {                 // coalesced ushort4 W^T rows
            const int orow = r0 + p * 16;
            ushort4 pk;
            pk.x = f2bf(tile[c4 + 0][orow]);
            pk.y = f2bf(tile[c4 + 1][orow]);
            pk.z = f2bf(tile[c4 + 2][orow]);
            pk.w = f2bf(tile[c4 + 3][orow]);
            *(ushort4*)&wbt[(size_t)(o0 + orow) * DIN + i0 + c4] = pk;
        }
    }
}

// ---------- GEMM + epilogue ----------
// 8-wave 128x256 tile, BK=64, tri-buffered LDS (distance-2 prefetch),
// counted vmcnt(6) (T4), 2 phases per K-tile {8 ds_read + 3 gload_lds ->
// barrier -> 16 MFMA (setprio, T5) -> barrier}, T2 both-sides swizzle.
// Grid 256 = 1 block/CU (full chip).
#define BM 128
#define BN 256
#define BK 64
#define NT (DIN / BK)        // 16 K-tiles
#define SA_ELTS (BM * BK)    // 8192 ushorts
#define SB_ELTS (BN * BK)    // 16384 ushorts
#define LDS_BYTES ((3 * SA_ELTS + 3 * SB_ELTS) * 2)  // 147456 = 144 KiB

// compiler-level fence around raw barriers: blocks hoisting LDS reads across
#define BARRIER() do { asm volatile("" ::: "memory");          \
                       __builtin_amdgcn_s_barrier();           \
                       asm volatile("" ::: "memory"); } while (0)

__global__ __launch_bounds__(512, 2) void gemm_epi(
    const ushort* __restrict__ A,
    const ushort* __restrict__ Bt,
    const float* __restrict__ xsq,
    const float* __restrict__ wsq_part,
    float* __restrict__ out)
{
    extern __shared__ __align__(16) char smem[];
    ushort* sAb = (ushort*)smem;                       // 3 x [128][64]
    ushort* sBb = (ushort*)(smem + 3 * SA_ELTS * 2);   // 3 x [256][64]

    const int tid  = threadIdx.x;
    const int wv   = tid >> 6;          // 0..7
    const int lane = tid & 63;
    const int wr = wv >> 2, wc = wv & 3;  // 2M x 4N wave grid, wave out 64x64

    // XCD-local mapping: grid 16x16 (by over BATCH, bx over DOUT). XCD k
    // (bid&7, HW round-robin) gets bx in [4*(k&3),+4), by in [8*(k>>2),+8):
    // working set = 4 A-panels (1 MiB) + 4 B-panels (2 MiB) + out <= L2.
    const int k = blockIdx.x & 7, loc = blockIdx.x >> 3;  // loc 0..31
    const int bx = (k & 3) * 4 + (loc & 3);
    const int by = (k >> 2) * 8 + (loc >> 2);
    const int m0 = by * BM;
    const int n0 = bx * BN;

    // ---- staging geometry ----
    // Rows of 64 bf16 = 128B = 8 chunks. Each gload_lds inst: 64 lanes -> 8
    // rows; lane l -> row base+(l>>3), phys slot l&7. Swizzle (both-sides):
    // LDS(row,ps) holds global chunk ps ^ (row&7); row&7 == l>>3 here.
    const int srow = wv * 8 + (lane >> 3);
    const int scol = ((lane & 7) ^ (lane >> 3)) << 3;   // ushorts
    const ushort* ag = A  + (size_t)(m0 + srow) * DIN + scol;
    const ushort* bg = Bt + (size_t)(n0 + srow) * DIN + scol;

    auto stA = [&](int b, int t, int q) {  // q in {0,1}: rows wv*8 + q*64
        async_copy16(ag + (size_t)t * BK + (size_t)q * 64 * DIN,
                     sAb + (size_t)b * SA_ELTS + (wv * 8 + q * 64) * BK);
    };
    auto stB = [&](int b, int t, int q) {  // q in {0..3}
        async_copy16(bg + (size_t)t * BK + (size_t)q * 64 * DIN,
                     sBb + (size_t)b * SB_ELTS + (wv * 8 + q * 64) * BK);
    };

    // ---- fragment geometry ----
    // A-op lane: m = lane&15, k = (lane>>4)*8+j. Logical chunk ks*4+(lane>>4),
    // physical = logical ^ (row&7); row&7 = (lane&15)&7 = lane&7.
    const int fr = lane & 15, q4 = lane >> 4, fr7 = lane & 7;
    const int cks[2] = { (q4 ^ fr7) << 3, ((4 + q4) ^ fr7) << 3 };
    const int arow0 = wr * 64 + fr;     // + mi*16, rows 0..127
    const int brow0 = wc * 64 + fr;     // + ni*16, rows 0..255

    f32x4 acc[4][4] = {};

// Phase: {8 ds_read_b128 | stage issue} -> barrier -> 16 MFMA -> close -> barrier
#define PHASE(CUR, KS, STAGE, CLOSE) do {                                   \
    const ushort* pa_ = sAb + (CUR) * SA_ELTS;                              \
    const ushort* pb_ = sBb + (CUR) * SB_ELTS;                              \
    bf16x8 fa[4], fb[4];                                                    \
    _Pragma("unroll") for (int i = 0; i < 4; ++i)                           \
        fa[i] = *(const bf16x8*)&pa_[(arow0 + i * 16) * BK + cks[KS]];      \
    _Pragma("unroll") for (int i = 0; i < 4; ++i)                           \
        fb[i] = *(const bf16x8*)&pb_[(brow0 + i * 16) * BK + cks[KS]];      \
    STAGE;                                                                  \
    BARRIER();                                                              \
    __builtin_amdgcn_s_setprio(1);                                          \
    _Pragma("unroll") for (int mi = 0; mi < 4; ++mi)                        \
    _Pragma("unroll") for (int ni = 0; ni < 4; ++ni)                        \
        acc[mi][ni] = __builtin_amdgcn_mfma_f32_16x16x32_bf16(              \
            fa[mi], fb[ni], acc[mi][ni], 0, 0, 0);                          \
    __builtin_amdgcn_s_setprio(0);                                          \
    CLOSE;                                                                  \
    BARRIER();                                                              \
} while (0)

    // Prologue: stage tiles 0,1 (12 loads/wave); wait tile0 (6 newest stay).
    stA(0, 0, 0); stA(0, 0, 1);
    stB(0, 0, 0); stB(0, 0, 1); stB(0, 0, 2); stB(0, 0, 3);
    stA(1, 1, 0); stA(1, 1, 1);
    stB(1, 1, 0); stB(1, 1, 1); stB(1, 1, 2); stB(1, 1, 3);
    asm volatile("s_waitcnt vmcnt(6)" ::: "memory");
    BARRIER();

    // Steady state per tile s: consume buf s%3; stage tile s+2 into (s+2)%3
    // (= buffer of tile s-1, whose reads finished before s's opening barrier).
    // Closing vmcnt(6): drains tile s+1's 6 loads, keeps tile s+2's 6 in
    // flight across the barrier (T4: never drain to 0 mid-loop).
    #pragma unroll
    for (int s = 0; s < NT - 2; ++s) {
        const int cur = s % 3, n3 = (s + 2) % 3, t2 = s + 2;
        PHASE(cur, 0, (stA(n3, t2, 0), stA(n3, t2, 1), stB(n3, t2, 0)),
              (void)0);
        PHASE(cur, 1, (stB(n3, t2, 1), stB(n3, t2, 2), stB(n3, t2, 3)),
              asm volatile("s_waitcnt vmcnt(6)" ::: "memory"));
    }
    // s = 14 (cur 2): no stage; drain tile 15's loads.
    PHASE(2, 0, (void)0, (void)0);
    PHASE(2, 1, (void)0, asm volatile("s_waitcnt vmcnt(0)" ::: "memory"));
    // s = 15 (cur 0): compute only.
    PHASE(0, 0, (void)0, (void)0);
    PHASE(0, 1, (void)0, (void)0);
#undef PHASE

    // Epilogue. C/D layout (m89/m91): col = lane&15, row = (lane>>4)*4 + r.
    const int er = q4 * 4;
    const int ec = fr;

    // wterm: sum 16 i-block partials per output column (L2-hit loads)
    float wt[4];
    #pragma unroll
    for (int ni = 0; ni < 4; ++ni) {
        const int col = n0 + wc * 64 + ni * 16 + ec;
        float s = 0.f;
        #pragma unroll
        for (int j = 0; j < 16; ++j) s += wsq_part[(size_t)j * DOUT + col];
        wt[ni] = s;
    }

    #pragma unroll
    for (int mi = 0; mi < 4; ++mi) {
        const int row = m0 + wr * 64 + mi * 16 + er;
        #pragma unroll
        for (int ni = 0; ni < 4; ++ni) {
            const int col = n0 + wc * 64 + ni * 16 + ec;
            #pragma unroll
            for (int r = 0; r < 4; ++r) {
                out[(size_t)(row + r) * DOUT + col] =
                    acc[mi][ni][r] - 0.5f * (xsq[row + r] + wt[ni]);
            }
        }
    }
}

// ---------- launch ----------

extern "C" void kernel_launch(void* const* d_in, const int* in_sizes, int n_in,
                              void* d_out, int out_size, void* d_ws, size_t ws_size,
                              hipStream_t stream) {
    const float* x = (const float*)d_in[0];
    const float* W = (const float*)d_in[1];
    float* out = (float*)d_out;

    // Workspace layout (~12.3 MiB):
    //   [0, 4MiB)              xb       : bf16 x   [2048][1024]
    //   [4MiB, 12MiB)          wbt      : bf16 W^T [4096][1024]
    //   [12MiB, +8KiB)         xsq      : f32 [2048]
    //   [12MiB+16KiB, +256KiB) wsq_part : f32 [16][4096]
    char* ws = (char*)d_ws;
    ushort* xb  = (ushort*)ws;
    ushort* wbt = (ushort*)(ws + (4u << 20));
    float*  xsq = (float*)(ws + (12u << 20));
    float*  wsq_part = (float*)(ws + (12u << 20) + (16u << 10));

    static bool attr_done = false;
    if (!attr_done) {
        hipFuncSetAttribute((const void*)gemm_epi,
                            hipFuncAttributeMaxDynamicSharedMemorySize,
                            LDS_BYTES);
        attr_done = true;
    }

    prep_fused<<<BATCH + (DOUT / 64) * (DIN / 64), 256, 0, stream>>>(
        x, W, xb, wbt, xsq, wsq_part);
    gemm_epi<<<(DOUT / BN) * (BATCH / BM), 512, LDS_BYTES, stream>>>(
        xb, wbt, xsq, wsq_part, out);
}

// Round 4
// 105.040 us; speedup vs baseline: 1.0396x; 1.0118x over previous
//
#include <hip/hip_runtime.h>
#include <stdint.h>

// Problem: x [2048][1024] f32, W [1024][4096] f32,
// out [2048][4096] f32 = x@W - 0.5*(||x_b||^2 + ||w_o||^2)
#define BATCH 2048
#define DIN   1024
#define DOUT  4096

// ---------- helpers ----------

// fp32 -> bf16 bits, round-to-nearest-even (finite normals; no NaN path)
__device__ __forceinline__ ushort f2bf(float f) {
    uint32_t u = __float_as_uint(f);
    u += 0x7fffu + ((u >> 16) & 1u);
    return (ushort)(u >> 16);
}

// async global->LDS direct copy, 16B per lane. LDS dest is wave-uniform base;
// HW writes lane i's 16B at ldsbase + i*16 (m97/m104).
__device__ __forceinline__ void async_copy16(const void* gsrc, void* ldst) {
    __builtin_amdgcn_global_load_lds(
        reinterpret_cast<uint32_t __attribute__((address_space(1)))*>(
            reinterpret_cast<uintptr_t>(gsrc)),
        reinterpret_cast<uint32_t __attribute__((address_space(3)))*>(
            reinterpret_cast<uintptr_t>(ldst)),
        16, 0, 0);
}

typedef __bf16 bf16x8 __attribute__((ext_vector_type(8)));
typedef float  f32x4  __attribute__((ext_vector_type(4)));

// ---------- fused prep (single dispatch, no memset, no global atomics) ----------
// blocks [0,2048): row of x -> bf16 cast + row sum-of-squares (xsq)
// blocks [2048,3072): 64x64 transpose tile of W -> bf16 W^T + column
//   sum-of-squares PARTIALS (wsq_part[16][DOUT])
__global__ __launch_bounds__(256) void prep_fused(
    const float* __restrict__ x, const float* __restrict__ W,
    ushort* __restrict__ xb, ushort* __restrict__ wbt,
    float* __restrict__ xsq, float* __restrict__ wsq_part)
{
    __shared__ float smem[64 * 65 + 64];  // prep_w tile + csum; prep_x uses [0..3]
    const int t = threadIdx.x;

    if (blockIdx.x < BATCH) {
        // ---- prep_x ----
        const int row = blockIdx.x;
        const float4 v = *(const float4*)(x + (size_t)row * DIN + t * 4);
        ushort4 pk;
        pk.x = f2bf(v.x); pk.y = f2bf(v.y); pk.z = f2bf(v.z); pk.w = f2bf(v.w);
        *(ushort4*)(xb + (size_t)row * DIN + t * 4) = pk;

        float s = v.x * v.x + v.y * v.y + v.z * v.z + v.w * v.w;
        #pragma unroll
        for (int off = 32; off > 0; off >>= 1) s += __shfl_down(s, off);
        if ((t & 63) == 0) smem[t >> 6] = s;
        __syncthreads();
        if (t == 0) xsq[row] = smem[0] + smem[1] + smem[2] + smem[3];
    } else {
        // ---- prep_w ----
        const int wblk = blockIdx.x - BATCH;          // 0..1023
        const int o0 = (wblk & 63) * 64;              // 64 chunks over DOUT
        const int i0 = (wblk >> 6) * 64;              // 16 chunks over DIN
        float (*tile)[65] = (float(*)[65])smem;       // +1 pad
        float* csum = smem + 64 * 65;
        const int c4 = (t & 15) * 4;
        const int r0 = t >> 4;

        if (t < 64) csum[t] = 0.f;
        __syncthreads();

        float ss0 = 0.f, ss1 = 0.f, ss2 = 0.f, ss3 = 0.f;
        #pragma unroll
        for (int p = 0; p < 4; ++p) {                 // coalesced float4 rows
            const int r = r0 + p * 16;
            const float4 v = *(const float4*)&W[(size_t)(i0 + r) * DOUT + o0 + c4];
            tile[r][c4 + 0] = v.x; tile[r][c4 + 1] = v.y;
            tile[r][c4 + 2] = v.z; tile[r][c4 + 3] = v.w;
            ss0 += v.x * v.x; ss1 += v.y * v.y;
            ss2 += v.z * v.z; ss3 += v.w * v.w;
        }
        atomicAdd(&csum[c4 + 0], ss0);
        atomicAdd(&csum[c4 + 1], ss1);
        atomicAdd(&csum[c4 + 2], ss2);
        atomicAdd(&csum[c4 + 3], ss3);
        __syncthreads();
        if (t < 64) wsq_part[(size_t)(wblk >> 6) * DOUT + o0 + t] = csum[t];

        #pragma unroll
        for (int p = 0; p < 4; ++p) {                 // coalesced ushort4 W^T rows
            const int orow = r0 + p * 16;
            ushort4 pk;
            pk.x = f2bf(tile[c4 + 0][orow]);
            pk.y = f2bf(tile[c4 + 1][orow]);
            pk.z = f2bf(tile[c4 + 2][orow]);
            pk.w = f2bf(tile[c4 + 3][orow]);
            *(ushort4*)&wbt[(size_t)(o0 + orow) * DIN + i0 + c4] = pk;
        }
    }
}

// ---------- GEMM + epilogue ----------
// R1's measured-best structure VERBATIM (104.6 us): 128x128 tile, BK=64,
// double-buffered LDS, one barrier pair per K-tile, distance-1 prefetch.
// Changes vs R1: XCD-local block mapping (8bx x 8by super-tile per XCD:
// 2 MiB B + 2 MiB A = exactly the 4 MiB private L2), setprio around MFMA,
// wsq from 16 partials in epilogue (no memset/atomics upstream).
#define BM 128
#define BN 128
#define BK 64
#define NT (DIN / BK)  // 16 K-tiles

__global__ __launch_bounds__(256, 2) void gemm_epi(
    const ushort* __restrict__ A,
    const ushort* __restrict__ Bt,
    const float* __restrict__ xsq,
    const float* __restrict__ wsq_part,
    float* __restrict__ out)
{
    __shared__ __align__(16) ushort sA[2][BM * BK];  // 2 x 16 KiB
    __shared__ __align__(16) ushort sB[2][BN * BK];  // 2 x 16 KiB

    const int tid  = threadIdx.x;
    const int wv   = tid >> 6;
    const int lane = tid & 63;
    const int wr = wv >> 1, wc = wv & 1;

    // XCD-local mapping: grid 512 = 32 bx x 16 by. XCD k (bid&7, HW
    // round-robin) gets an 8bx x 8by super-tile; its L2 working set is
    // 8 B-panels (2 MiB) + 8 A-panels (2 MiB) = 4 MiB. 512%8==0 (bijective).
    const int bid = blockIdx.x;
    const int k = bid & 7, loc = bid >> 3;           // loc 0..63
    const int bx = (k & 3) * 8 + (loc & 7);          // 0..31 over DOUT
    const int by = (k >> 2) * 8 + (loc >> 3);        // 0..15 over BATCH
    const int m0 = by * BM;
    const int n0 = bx * BN;

    // ---- staging geometry (R1, verified) ----
    // Tile row-major [128][64] ushort (128B row = 8 chunks of 16B).
    // Dest chunk (linear HW order): c = q*256 + tid; row = c>>3, slot = tid&7.
    // LDS(row, slot) holds global chunk (slot ^ (row&7)) -> pre-swizzled src.
    const int srow = tid >> 3;                           // 0..31, +q*32
    const int scol = (((tid & 7) ^ (srow & 7)) << 3);    // swizzled k-off (ushorts)
    const ushort* ag = A  + (size_t)(m0 + srow) * DIN + scol;
    const ushort* bg = Bt + (size_t)(n0 + srow) * DIN + scol;

    // ---- fragment geometry (R1, verified) ----
    // A-op lane holds A[m=lane&15][k=(lane>>4)*8+j]; logical slot ks*4+(lane>>4),
    // physical = ^ (row&7); row&7 == lane&7 for all fragment rows.
    const int fr  = lane & 15;
    const int q4  = lane >> 4;
    const int x7  = lane & 7;
    const int arow = wr * 64 + fr;
    const int brow = wc * 64 + fr;
    const int sl0 = ((q4)     ^ x7) << 3;  // ushort offset within row, ks=0
    const int sl1 = ((4 + q4) ^ x7) << 3;  // ks=1

    f32x4 acc[4][4] = {};

    auto stage = [&](int b, int kt) {
        ushort* da = &sA[b][0] + wv * 512;   // wave-uniform base, HW adds lane*16B
        ushort* db = &sB[b][0] + wv * 512;
        #pragma unroll
        for (int q = 0; q < 4; ++q) {
            async_copy16(ag + (size_t)q * 32 * DIN + kt, da + q * 2048);
            async_copy16(bg + (size_t)q * 32 * DIN + kt, db + q * 2048);
        }
    };

    stage(0, 0);
    __syncthreads();   // compiler emits vmcnt(0) drain before s_barrier
    int cur = 0;

    for (int t = 0; t < NT; ++t) {
        if (t + 1 < NT) stage(cur ^ 1, (t + 1) * BK);  // prefetch next K-tile

        const ushort* pa = &sA[cur][0];
        const ushort* pb = &sB[cur][0];
        bf16x8 fa[2][4], fb[2][4];
        #pragma unroll
        for (int i = 0; i < 4; ++i) {
            fa[0][i] = *(const bf16x8*)&pa[(arow + i * 16) * BK + sl0];
            fa[1][i] = *(const bf16x8*)&pa[(arow + i * 16) * BK + sl1];
            fb[0][i] = *(const bf16x8*)&pb[(brow + i * 16) * BK + sl0];
            fb[1][i] = *(const bf16x8*)&pb[(brow + i * 16) * BK + sl1];
        }

        __builtin_amdgcn_s_setprio(1);
        #pragma unroll
        for (int ks = 0; ks < 2; ++ks)
            #pragma unroll
            for (int mi = 0; mi < 4; ++mi)
                #pragma unroll
                for (int ni = 0; ni < 4; ++ni)
                    acc[mi][ni] = __builtin_amdgcn_mfma_f32_16x16x32_bf16(
                        fa[ks][mi], fb[ks][ni], acc[mi][ni], 0, 0, 0);
        __builtin_amdgcn_s_setprio(0);

        __syncthreads();  // vmcnt(0): prefetched tile landed; all waves done
                          // reading buf[cur] (their lgkmcnt(0) preceded MFMA)
        cur ^= 1;
    }

    // Epilogue. C/D layout (m89/m91): col = lane&15, row = (lane>>4)*4 + r.
    const int er = q4 * 4;
    const int ec = fr;

    // wterm: sum the 16 i-block partials per output column (L2-hit loads)
    float wt[4];
    #pragma unroll
    for (int ni = 0; ni < 4; ++ni) {
        const int col = n0 + wc * 64 + ni * 16 + ec;
        float s = 0.f;
        #pragma unroll
        for (int j = 0; j < 16; ++j) s += wsq_part[(size_t)j * DOUT + col];
        wt[ni] = s;
    }

    #pragma unroll
    for (int mi = 0; mi < 4; ++mi) {
        const int row = m0 + wr * 64 + mi * 16 + er;
        #pragma unroll
        for (int ni = 0; ni < 4; ++ni) {
            const int col = n0 + wc * 64 + ni * 16 + ec;
            #pragma unroll
            for (int r = 0; r < 4; ++r) {
                out[(size_t)(row + r) * DOUT + col] =
                    acc[mi][ni][r] - 0.5f * (xsq[row + r] + wt[ni]);
            }
        }
    }
}

// ---------- launch ----------

extern "C" void kernel_launch(void* const* d_in, const int* in_sizes, int n_in,
                              void* d_out, int out_size, void* d_ws, size_t ws_size,
                              hipStream_t stream) {
    const float* x = (const float*)d_in[0];
    const float* W = (const float*)d_in[1];
    float* out = (float*)d_out;

    // Workspace layout (~12.3 MiB):
    //   [0, 4MiB)              xb       : bf16 x   [2048][1024]
    //   [4MiB, 12MiB)          wbt      : bf16 W^T [4096][1024]
    //   [12MiB, +8KiB)         xsq      : f32 [2048]
    //   [12MiB+16KiB, +256KiB) wsq_part : f32 [16][4096]
    char* ws = (char*)d_ws;
    ushort* xb  = (ushort*)ws;
    ushort* wbt = (ushort*)(ws + (4u << 20));
    float*  xsq = (float*)(ws + (12u << 20));
    float*  wsq_part = (float*)(ws + (12u << 20) + (16u << 10));

    prep_fused<<<BATCH + (DOUT / 64) * (DIN / 64), 256, 0, stream>>>(
        x, W, xb, wbt, xsq, wsq_part);
    gemm_epi<<<(DOUT / BN) * (BATCH / BM), 256, 0, stream>>>(
        xb, wbt, xsq, wsq_part, out);
}